// Round 2
// baseline (1206.738 us; speedup 1.0000x reference)
//
#include <hip/hip_runtime.h>

// LightGCN: 3 SpMM layers, 100K nodes x 128 dims, 6.4M edges.
// R7: dim-split XCD-pinned propagation. R5/R6 both pinned at 3.8 TB/s fetch
// with ~760 MB L2-miss traffic per layer (gather pool 25.6 MB >> 4 MB per-XCD
// L2 -> ~50% miss). Split 128 dims into 8 slices of 16; blockIdx.x & 7 pins
// slice s to XCD s (round-robin dispatch heuristic). Per-XCD gather footprint
// = 3.2 MB < 4 MB L2 -> gathers become L2 hits; per-layer miss traffic ~3x
// lower (csr stream 205 MB + cold fills). x layout: [split][node][16 dims].
// Group = 16 lanes per row: 8 edges/step, 2 lanes/edge (uint4 = 8 bf16 dims),
// coalesced 8-dword csr loads, 2-stage pipeline, shfl_xor(2,4,8) reduce.
// CSR build (two-level counting sort) unchanged.

#define RPB 512
#define RPB_SHIFT 9
#define TILE_EPT 16   // edges per thread in bin_edges (tile = 4096)
#define NSPLIT 8      // dim slices == XCD count
#define UPS 8         // uints per node per split (16 dims bf16 = 32B)

__device__ __forceinline__ unsigned bf16r(float f) {
    unsigned u = __float_as_uint(f);
    return (u + 0x7fffu + ((u >> 16) & 1u)) >> 16;
}
__device__ __forceinline__ unsigned packbf(float lo, float hi) {
    return bf16r(lo) | (bf16r(hi) << 16);
}
__device__ __forceinline__ float blo(unsigned u) { return __uint_as_float(u << 16); }
__device__ __forceinline__ float bhi(unsigned u) { return __uint_as_float(u & 0xffff0000u); }

// ---- Pass A: bucket histogram (LDS-aggregated) ----
__global__ __launch_bounds__(256) void bucket_count(
    const int* __restrict__ rows, int* __restrict__ bcount, int n_edges, int NB) {
    __shared__ int hist[512];
    for (int i = threadIdx.x; i < NB; i += 256) hist[i] = 0;
    __syncthreads();
    int idx = blockIdx.x * blockDim.x + threadIdx.x;
    int stride = gridDim.x * blockDim.x;
    for (int e = idx; e < n_edges; e += stride)
        atomicAdd(&hist[rows[e] >> RPB_SHIFT], 1);
    __syncthreads();
    for (int i = threadIdx.x; i < NB; i += 256)
        if (hist[i]) atomicAdd(&bcount[i], hist[i]);
}

// ---- Scan bucket counts (NB <= 512) ----
__global__ void bucket_scan(const int* __restrict__ bcount, int* __restrict__ bbase,
                            int* __restrict__ bcursor, int NB, int n_edges) {
    __shared__ int tmp[512];
    int v = ((int)threadIdx.x < NB) ? bcount[threadIdx.x] : 0;
    tmp[threadIdx.x] = v;
    __syncthreads();
    for (int off = 1; off < 512; off <<= 1) {
        int t = (threadIdx.x >= (unsigned)off) ? tmp[threadIdx.x - off] : 0;
        __syncthreads();
        tmp[threadIdx.x] += t;
        __syncthreads();
    }
    if ((int)threadIdx.x < NB) {
        int ex = tmp[threadIdx.x] - v;
        bbase[threadIdx.x] = ex;
        bcursor[threadIdx.x] = ex;
    }
    if (threadIdx.x == 0) bbase[NB] = n_edges;
}

// ---- Pass B: bin edges into bucket-major pairs (row, payload) ----
__global__ __launch_bounds__(256) void bin_edges(
    const int* __restrict__ rows, const int* __restrict__ cols,
    const float* __restrict__ vals, int* __restrict__ bcursor,
    uint2* __restrict__ pairs, int n_edges, int NB) {
    __shared__ int hist[512];
    for (int i = threadIdx.x; i < NB; i += 256) hist[i] = 0;
    __syncthreads();
    int tile0 = blockIdx.x * (256 * TILE_EPT);
    int r[TILE_EPT], b[TILE_EPT];
    #pragma unroll
    for (int k = 0; k < TILE_EPT; ++k) {
        int e = tile0 + k * 256 + threadIdx.x;
        r[k] = -1;
        if (e < n_edges) {
            r[k] = rows[e];
            b[k] = r[k] >> RPB_SHIFT;
            atomicAdd(&hist[b[k]], 1);
        }
    }
    __syncthreads();
    for (int i = threadIdx.x; i < NB; i += 256) {
        int h = hist[i];
        int base = h ? atomicAdd(&bcursor[i], h) : 0;
        hist[i] = base;  // hist becomes global cursor
    }
    __syncthreads();
    #pragma unroll
    for (int k = 0; k < TILE_EPT; ++k) {
        int e = tile0 + k * 256 + threadIdx.x;
        if (r[k] >= 0) {
            int pos = atomicAdd(&hist[b[k]], 1);
            int q = __float2int_rn(vals[e] * 1638400.0f);  // * 32768/0.02
            q = min(q, 32767);
            unsigned pk = ((unsigned)cols[e] << 15) | (unsigned)q;
            pairs[pos] = make_uint2((unsigned)r[k], pk);
        }
    }
}

// ---- Pass C: per-bucket fine counting sort -> row_start + packed csr ----
__global__ __launch_bounds__(256) void build_csr(
    const uint2* __restrict__ pairs, const int* __restrict__ bbase,
    int* __restrict__ row_start, unsigned* __restrict__ csr,
    int n_nodes, int n_edges, int NB) {
    __shared__ int cnt[RPB];
    __shared__ int cur[RPB];
    int bkt = blockIdx.x;
    int row0 = bkt << RPB_SHIFT;
    int nrows = n_nodes - row0;
    if (nrows > RPB) nrows = RPB;
    int s = bbase[bkt], e = bbase[bkt + 1];
    for (int i = threadIdx.x; i < RPB; i += 256) cnt[i] = 0;
    __syncthreads();
    for (int i = s + threadIdx.x; i < e; i += 256)
        atomicAdd(&cnt[pairs[i].x - row0], 1);
    __syncthreads();
    if (threadIdx.x < 64) {
        int lane = threadIdx.x;
        int v[8]; int sum = 0;
        #pragma unroll
        for (int j = 0; j < 8; ++j) { v[j] = cnt[lane * 8 + j]; sum += v[j]; }
        int inc = sum;
        #pragma unroll
        for (int off = 1; off < 64; off <<= 1) {
            int t = __shfl_up(inc, off);
            if (lane >= off) inc += t;
        }
        int ex = inc - sum;
        #pragma unroll
        for (int j = 0; j < 8; ++j) {
            cnt[lane * 8 + j] = ex;
            cur[lane * 8 + j] = ex;
            ex += v[j];
        }
    }
    __syncthreads();
    for (int i = threadIdx.x; i < nrows; i += 256)
        row_start[row0 + i] = s + cnt[i];
    if (bkt == NB - 1 && threadIdx.x == 0) row_start[n_nodes] = n_edges;
    for (int i = s + threadIdx.x; i < e; i += 256) {
        uint2 p = pairs[i];
        int pos = atomicAdd(&cur[p.x - row0], 1);
        csr[s + pos] = p.y;
    }
}

// ---- emb fp32 -> x0 bf16, split layout [split][node][8 uints] ----
__global__ __launch_bounds__(256) void init_pack_split(
    const float* __restrict__ emb, unsigned* __restrict__ x0,
    int n_nodes, int sstride) {
    int t = blockIdx.x * 256 + threadIdx.x;
    if (t >= n_nodes * 16) return;
    int n = t >> 4;
    int s = (t >> 1) & 7;
    int h = t & 1;
    const float4* ef = (const float4*)(emb + (size_t)n * 128 + s * 16 + h * 8);
    float4 a = ef[0], b = ef[1];
    uint4 o;
    o.x = packbf(a.x, a.y);
    o.y = packbf(a.z, a.w);
    o.z = packbf(b.x, b.y);
    o.w = packbf(b.z, b.w);
    *(uint4*)(x0 + (size_t)s * sstride + (size_t)n * UPS + h * 4) = o;
}

// ---- Propagation core (split form): 16-lane group = 1 row x 1 dim-slice.
// 8 edges/step, 2 lanes/edge: lane (eo = gl>>1, h = gl&1) gathers uint4 =
// 8 bf16 dims of edge eo. csr loads coalesced (8 consecutive dwords/group).
// 2-stage pipeline. Butterfly shfl_xor(2,4,8) reduces the 8 eo-partials. ----
__device__ __forceinline__ unsigned ldpe(const unsigned* __restrict__ csr, int idx, int e) {
    int i = idx < e ? idx : (e - 1);
    unsigned x = csr[i];
    return idx < e ? x : 0u;
}
__device__ __forceinline__ uint4 gth(const unsigned* __restrict__ xs,
                                     unsigned pe, int h4) {
    return *(const uint4*)(xs + ((pe >> 15) * UPS) + h4);
}
__device__ __forceinline__ void fma8(float acc[8], unsigned pe, uint4 g) {
    float v = (float)(pe & 0x7fffu) * 6.103515625e-7f;  // q * 0.02/32768
    acc[0] = fmaf(v, blo(g.x), acc[0]);
    acc[1] = fmaf(v, bhi(g.x), acc[1]);
    acc[2] = fmaf(v, blo(g.y), acc[2]);
    acc[3] = fmaf(v, bhi(g.y), acc[3]);
    acc[4] = fmaf(v, blo(g.z), acc[4]);
    acc[5] = fmaf(v, bhi(g.z), acc[5]);
    acc[6] = fmaf(v, blo(g.w), acc[6]);
    acc[7] = fmaf(v, bhi(g.w), acc[7]);
}

__device__ __forceinline__ void accum_row_split(
    const unsigned* __restrict__ csr, const unsigned* __restrict__ xs,
    int eo, int h4, int s, int e, float acc[8]) {
    unsigned pA, pB;
    uint4 gA, gB;
    int jb = s;
    if (jb < e) {
        pA = ldpe(csr, jb + eo, e);
        gA = gth(xs, pA, h4);
    }
    while (jb < e) {
        int jn = jb + 8;
        if (jn < e) {
            pB = ldpe(csr, jn + eo, e);
            gB = gth(xs, pB, h4);
        }
        fma8(acc, pA, gA);
        jb = jn;
        if (jb >= e) break;
        jn = jb + 8;
        if (jn < e) {
            pA = ldpe(csr, jn + eo, e);
            gA = gth(xs, pA, h4);
        }
        fma8(acc, pB, gB);
        jb = jn;
    }
    // Reduce the 8 per-eo partials (lanes with equal h, stride 2 in group).
    #pragma unroll
    for (int i = 0; i < 8; ++i) {
        acc[i] += __shfl_xor(acc[i], 2);
        acc[i] += __shfl_xor(acc[i], 4);
        acc[i] += __shfl_xor(acc[i], 8);
    }
}

__global__ __launch_bounds__(256) void prop_mid(
    const int* __restrict__ row_start, const unsigned* __restrict__ csr,
    const unsigned* __restrict__ xin, unsigned* __restrict__ xout,
    int n_nodes, int sstride) {
    int split = blockIdx.x & 7;        // XCD-pinned dim slice
    int tile = blockIdx.x >> 3;
    int wave = threadIdx.x >> 6, lane = threadIdx.x & 63;
    int grp = lane >> 4, gl = lane & 15;
    int eo = gl >> 1, h4 = (gl & 1) * 4;
    int row = tile * 16 + wave * 4 + grp;
    if (row >= n_nodes) return;
    int s = row_start[row], e = row_start[row + 1];
    const unsigned* xs = xin + (size_t)split * sstride;
    float acc[8] = {0, 0, 0, 0, 0, 0, 0, 0};
    accum_row_split(csr, xs, eo, h4, s, e, acc);
    if (eo == 0) {
        uint4 o;
        o.x = packbf(acc[0], acc[1]);
        o.y = packbf(acc[2], acc[3]);
        o.z = packbf(acc[4], acc[5]);
        o.w = packbf(acc[6], acc[7]);
        *(uint4*)(xout + (size_t)split * sstride + (size_t)row * UPS + h4) = o;
    }
}

// Final layer: x3 = A*x2 fused with out = (emb + x1 + x2 + x3) / 4.
__global__ __launch_bounds__(256) void prop_last(
    const int* __restrict__ row_start, const unsigned* __restrict__ csr,
    const unsigned* __restrict__ x2, const unsigned* __restrict__ x1,
    const float* __restrict__ emb, float* __restrict__ out,
    int n_nodes, int sstride) {
    int split = blockIdx.x & 7;
    int tile = blockIdx.x >> 3;
    int wave = threadIdx.x >> 6, lane = threadIdx.x & 63;
    int grp = lane >> 4, gl = lane & 15;
    int eo = gl >> 1, h4 = (gl & 1) * 4;
    int row = tile * 16 + wave * 4 + grp;
    if (row >= n_nodes) return;
    int s = row_start[row], e = row_start[row + 1];
    const unsigned* xs = x2 + (size_t)split * sstride;
    float acc[8] = {0, 0, 0, 0, 0, 0, 0, 0};
    accum_row_split(csr, xs, eo, h4, s, e, acc);
    if (eo == 0) {
        size_t xo = (size_t)split * sstride + (size_t)row * UPS + h4;
        uint4 p1 = *(const uint4*)(x1 + xo);
        uint4 p2 = *(const uint4*)(x2 + xo);
        int d0 = split * 16 + (h4 >> 2) * 8;  // first fp32 dim of this lane
        const float4* ef = (const float4*)(emb + (size_t)row * 128 + d0);
        float4 e0 = ef[0], e1 = ef[1];
        float4 r0, r1;
        r0.x = (e0.x + blo(p1.x) + blo(p2.x) + acc[0]) * 0.25f;
        r0.y = (e0.y + bhi(p1.x) + bhi(p2.x) + acc[1]) * 0.25f;
        r0.z = (e0.z + blo(p1.y) + blo(p2.y) + acc[2]) * 0.25f;
        r0.w = (e0.w + bhi(p1.y) + bhi(p2.y) + acc[3]) * 0.25f;
        r1.x = (e1.x + blo(p1.z) + blo(p2.z) + acc[4]) * 0.25f;
        r1.y = (e1.y + bhi(p1.z) + bhi(p2.z) + acc[5]) * 0.25f;
        r1.z = (e1.z + blo(p1.w) + blo(p2.w) + acc[6]) * 0.25f;
        r1.w = (e1.w + bhi(p1.w) + bhi(p2.w) + acc[7]) * 0.25f;
        float4* of = (float4*)(out + (size_t)row * 128 + d0);
        of[0] = r0;
        of[1] = r1;
    }
}

extern "C" void kernel_launch(void* const* d_in, const int* in_sizes, int n_in,
                              void* d_out, int out_size, void* d_ws, size_t ws_size,
                              hipStream_t stream) {
    const float* emb  = (const float*)d_in[0];
    const int*   rows = (const int*)d_in[1];
    const int*   cols = (const int*)d_in[2];
    const float* vals = (const float*)d_in[3];
    float* out = (float*)d_out;

    const int n_nodes = in_sizes[0] / 128;  // 100000
    const int n_edges = in_sizes[1];        // 6400000
    const int NB = (n_nodes + RPB - 1) >> RPB_SHIFT;  // 196 (<= 512)
    const int sstride = n_nodes * UPS;      // uints per split slice

    char* ws = (char*)d_ws;
    size_t off = 0;
    auto alloc = [&](size_t bytes) -> void* {
        void* p = ws + off;
        off += (bytes + 255) & ~(size_t)255;
        return p;
    };
    unsigned* x0        = (unsigned*)alloc((size_t)n_nodes * 64 * 4);   // 25.6 MB
    unsigned* x1        = (unsigned*)alloc((size_t)n_nodes * 64 * 4);   // 25.6 MB
    unsigned* x2        = (unsigned*)alloc((size_t)n_nodes * 64 * 4);   // 25.6 MB
    unsigned* csr       = (unsigned*)alloc((size_t)n_edges * 4);        // 25.6 MB
    uint2*    pairs     = (uint2*)alloc((size_t)n_edges * 8);           // 51.2 MB
    int*      row_start = (int*)alloc((size_t)(n_nodes + 1) * 4);
    int*      bcount    = (int*)alloc(520 * 4);
    int*      bbase     = (int*)alloc(520 * 4);
    int*      bcursor   = (int*)alloc(520 * 4);
    (void)ws_size;

    // ---- Build CSR via two-level counting sort ----
    hipMemsetAsync(bcount, 0, 520 * 4, stream);
    bucket_count<<<512, 256, 0, stream>>>(rows, bcount, n_edges, NB);
    bucket_scan<<<1, 512, 0, stream>>>(bcount, bbase, bcursor, NB, n_edges);
    const int tiles = (n_edges + 256 * TILE_EPT - 1) / (256 * TILE_EPT);
    bin_edges<<<tiles, 256, 0, stream>>>(rows, cols, vals, bcursor, pairs, n_edges, NB);
    build_csr<<<NB, 256, 0, stream>>>(pairs, bbase, row_start, csr, n_nodes, n_edges, NB);

    // ---- x0 = bf16(emb), split layout ----
    const int ipt = n_nodes * 16;
    init_pack_split<<<(ipt + 255) / 256, 256, 0, stream>>>(emb, x0, n_nodes, sstride);

    // ---- 3 layers: grid = row-tiles x 8 splits (split = blockIdx & 7) ----
    const int rtiles = (n_nodes + 15) / 16;
    const int gb = rtiles * NSPLIT;
    prop_mid<<<gb, 256, 0, stream>>>(row_start, csr, x0, x1, n_nodes, sstride);
    prop_mid<<<gb, 256, 0, stream>>>(row_start, csr, x1, x2, n_nodes, sstride);
    prop_last<<<gb, 256, 0, stream>>>(row_start, csr, x2, x1, emb, out, n_nodes, sstride);
}

// Round 3
// 995.538 us; speedup vs baseline: 1.2121x; 1.2121x over previous
//
#include <hip/hip_runtime.h>

// LightGCN: 3 SpMM layers, 100K nodes x 128 dims, 6.4M edges.
// R8: source-chunked propagation. R7 proved L2-residency cuts fetch 2.3x but
// 32B granules quadruple L1 line lookups (dur regressed). R8 keeps R6's full
// 256B-row gathers AND makes the gather pool L2-resident by TEMPORAL chunking:
// csr is sorted by (row, col>>13) -> 13 source chunks of 8192 nodes (2MB).
// Propagate launches exactly one resident wave (1024 blocks, 4/CU): all blocks
// start together and sweep chunks in lockstep-by-construction (no grid sync;
// drift after 13 phases ~0.6 phase -> working set 1-2 chunks <= L2). Each
// block holds 7 row-tiles' accumulators in registers (acc[7][8], static
// indexing); per-(row,chunk) bounds come from rcs[], emitted for free by the
// fine counting sort with key (local_row<<4)|chunk (8192 counters, 32KB LDS).

#define RPB 512
#define RPB_SHIFT 9
#define TILE_EPT 16    // edges per thread in bin_edges (tile = 4096)
#define CHSH 13        // source chunk = col >> 13 (8192 nodes = 2MB bf16)
#define PROP_GRID 1024 // one resident wave: 4 blocks/CU x 256 CU
#define TPROP 7        // row tiles per block: ceil(100000 / (1024*16))
#define ROWSTRIDE (PROP_GRID * 16)

__device__ __forceinline__ unsigned bf16r(float f) {
    unsigned u = __float_as_uint(f);
    return (u + 0x7fffu + ((u >> 16) & 1u)) >> 16;
}
__device__ __forceinline__ unsigned packbf(float lo, float hi) {
    return bf16r(lo) | (bf16r(hi) << 16);
}
__device__ __forceinline__ float blo(unsigned u) { return __uint_as_float(u << 16); }
__device__ __forceinline__ float bhi(unsigned u) { return __uint_as_float(u & 0xffff0000u); }

// ---- Pass A: bucket histogram (LDS-aggregated) ----
__global__ __launch_bounds__(256) void bucket_count(
    const int* __restrict__ rows, int* __restrict__ bcount, int n_edges, int NB) {
    __shared__ int hist[512];
    for (int i = threadIdx.x; i < NB; i += 256) hist[i] = 0;
    __syncthreads();
    int idx = blockIdx.x * blockDim.x + threadIdx.x;
    int stride = gridDim.x * blockDim.x;
    for (int e = idx; e < n_edges; e += stride)
        atomicAdd(&hist[rows[e] >> RPB_SHIFT], 1);
    __syncthreads();
    for (int i = threadIdx.x; i < NB; i += 256)
        if (hist[i]) atomicAdd(&bcount[i], hist[i]);
}

// ---- Scan bucket counts (NB <= 512) ----
__global__ void bucket_scan(const int* __restrict__ bcount, int* __restrict__ bbase,
                            int* __restrict__ bcursor, int NB, int n_edges) {
    __shared__ int tmp[512];
    int v = ((int)threadIdx.x < NB) ? bcount[threadIdx.x] : 0;
    tmp[threadIdx.x] = v;
    __syncthreads();
    for (int off = 1; off < 512; off <<= 1) {
        int t = (threadIdx.x >= (unsigned)off) ? tmp[threadIdx.x - off] : 0;
        __syncthreads();
        tmp[threadIdx.x] += t;
        __syncthreads();
    }
    if ((int)threadIdx.x < NB) {
        int ex = tmp[threadIdx.x] - v;
        bbase[threadIdx.x] = ex;
        bcursor[threadIdx.x] = ex;
    }
    if (threadIdx.x == 0) bbase[NB] = n_edges;
}

// ---- Pass B: bin edges into bucket-major pairs (row, payload) ----
__global__ __launch_bounds__(256) void bin_edges(
    const int* __restrict__ rows, const int* __restrict__ cols,
    const float* __restrict__ vals, int* __restrict__ bcursor,
    uint2* __restrict__ pairs, int n_edges, int NB) {
    __shared__ int hist[512];
    for (int i = threadIdx.x; i < NB; i += 256) hist[i] = 0;
    __syncthreads();
    int tile0 = blockIdx.x * (256 * TILE_EPT);
    int r[TILE_EPT], b[TILE_EPT];
    #pragma unroll
    for (int k = 0; k < TILE_EPT; ++k) {
        int e = tile0 + k * 256 + threadIdx.x;
        r[k] = -1;
        if (e < n_edges) {
            r[k] = rows[e];
            b[k] = r[k] >> RPB_SHIFT;
            atomicAdd(&hist[b[k]], 1);
        }
    }
    __syncthreads();
    for (int i = threadIdx.x; i < NB; i += 256) {
        int h = hist[i];
        int base = h ? atomicAdd(&bcursor[i], h) : 0;
        hist[i] = base;  // hist becomes global cursor
    }
    __syncthreads();
    #pragma unroll
    for (int k = 0; k < TILE_EPT; ++k) {
        int e = tile0 + k * 256 + threadIdx.x;
        if (r[k] >= 0) {
            int pos = atomicAdd(&hist[b[k]], 1);
            int q = __float2int_rn(vals[e] * 1638400.0f);  // * 32768/0.02
            q = min(q, 32767);
            unsigned pk = ((unsigned)cols[e] << 15) | (unsigned)q;
            pairs[pos] = make_uint2((unsigned)r[k], pk);
        }
    }
}

// ---- Pass C: per-bucket counting sort by (local_row, chunk) ->
//      rcs[(row)*nch + c] boundaries + csr payloads sorted by (row, chunk).
//      Row ends come from the next row's chunk-0 start (global contiguity);
//      single sentinel rcs[n_nodes*nch] = n_edges. ----
__global__ __launch_bounds__(256) void build_csr(
    const uint2* __restrict__ pairs, const int* __restrict__ bbase,
    int* __restrict__ rcs, unsigned* __restrict__ csr,
    int n_nodes, int n_edges, int NB, int nch) {
    __shared__ int cnt[RPB * 16];  // key = (local_row << 4) | chunk, 32KB
    __shared__ int wsum[4];
    int bkt = blockIdx.x;
    int row0 = bkt << RPB_SHIFT;
    int nrows = n_nodes - row0;
    if (nrows > RPB) nrows = RPB;
    int s = bbase[bkt], e = bbase[bkt + 1];
    int tid = threadIdx.x;
    for (int i = tid; i < RPB * 16; i += 256) cnt[i] = 0;
    __syncthreads();
    for (int i = s + tid; i < e; i += 256) {
        uint2 p = pairs[i];
        int key = ((int)(p.x - row0) << 4) | (int)(p.y >> 28);  // chunk = col>>13
        atomicAdd(&cnt[key], 1);
    }
    __syncthreads();
    // exclusive scan of 8192 counters: thread owns 32, wave scan + wave sums
    int base = tid * 32;
    int lsum = 0;
    #pragma unroll
    for (int j = 0; j < 32; ++j) lsum += cnt[base + j];
    int lane = tid & 63, w = tid >> 6;
    int inc = lsum;
    #pragma unroll
    for (int off = 1; off < 64; off <<= 1) {
        int t2 = __shfl_up(inc, off);
        if (lane >= off) inc += t2;
    }
    if (lane == 63) wsum[w] = inc;
    __syncthreads();
    int wadd = 0;
    for (int k = 0; k < w; ++k) wadd += wsum[k];
    int run = wadd + inc - lsum;
    #pragma unroll
    for (int j = 0; j < 32; ++j) { int v = cnt[base + j]; cnt[base + j] = run; run += v; }
    __syncthreads();
    // emit rcs boundaries
    for (int r = tid; r < nrows; r += 256) {
        int rb = (row0 + r) * nch;
        for (int c = 0; c < nch; ++c)
            rcs[rb + c] = s + cnt[(r << 4) | c];
    }
    if (bkt == NB - 1 && tid == 0) rcs[n_nodes * nch] = n_edges;
    __syncthreads();
    // scatter (cnt is now the cursor)
    for (int i = s + tid; i < e; i += 256) {
        uint2 p = pairs[i];
        int key = ((int)(p.x - row0) << 4) | (int)(p.y >> 28);
        int pos = atomicAdd(&cnt[key], 1);
        csr[s + pos] = p.y;
    }
}

// ---- emb fp32 -> x0 bf16x2-packed (flat [node][64 uints]) ----
__global__ void init_pack(const float4* __restrict__ emb, uint2* __restrict__ x0, int n4) {
    int i = blockIdx.x * blockDim.x + threadIdx.x;
    if (i < n4) {
        float4 v = emb[i];
        x0[i] = make_uint2(packbf(v.x, v.y), packbf(v.z, v.w));
    }
}

// ---- Propagation: 16-lane group = 1 row (lane owns 8 dims, 16B gather).
// Block owns 7 row-tiles (acc[7][8] in regs, static idx). Chunk-major sweep:
// all 1024 co-resident blocks process chunk c together -> gathers L2-hit. ----
__device__ __forceinline__ unsigned ldpe(const unsigned* __restrict__ csr, int idx, int e) {
    int i = idx < e ? idx : (e - 1);
    unsigned x = csr[i];
    return idx < e ? x : 0u;
}
__device__ __forceinline__ uint4 gth(const unsigned* __restrict__ xs,
                                     unsigned pe, unsigned loff) {
    return *(const uint4*)(xs + ((pe >> 15) << 6) + loff);
}
__device__ __forceinline__ void fma8(float acc[8], unsigned pe, uint4 g) {
    float v = (float)(pe & 0x7fffu) * 6.103515625e-7f;  // q * 0.02/32768
    acc[0] = fmaf(v, blo(g.x), acc[0]);
    acc[1] = fmaf(v, bhi(g.x), acc[1]);
    acc[2] = fmaf(v, blo(g.y), acc[2]);
    acc[3] = fmaf(v, bhi(g.y), acc[3]);
    acc[4] = fmaf(v, blo(g.z), acc[4]);
    acc[5] = fmaf(v, bhi(g.z), acc[5]);
    acc[6] = fmaf(v, blo(g.w), acc[6]);
    acc[7] = fmaf(v, bhi(g.w), acc[7]);
}

__device__ __forceinline__ void sweep_chunks(
    const int* __restrict__ rcs, const unsigned* __restrict__ csr,
    const unsigned* __restrict__ xin, int base, unsigned loff,
    int n_nodes, int nch, float acc[TPROP][8]) {
    for (int c = 0; c < nch; ++c) {
        int sA[TPROP], eA[TPROP];
        #pragma unroll
        for (int t = 0; t < TPROP; ++t) {
            int row = base + t * ROWSTRIDE;
            sA[t] = 0; eA[t] = 0;
            if (row < n_nodes) {
                int rb = row * nch + c;
                sA[t] = rcs[rb];
                eA[t] = rcs[rb + 1];
            }
        }
        #pragma unroll
        for (int t = 0; t < TPROP; ++t) {
            for (int jb = sA[t]; jb < eA[t]; jb += 4) {
                int ee = eA[t];
                unsigned p0 = ldpe(csr, jb + 0, ee), p1 = ldpe(csr, jb + 1, ee);
                unsigned p2 = ldpe(csr, jb + 2, ee), p3 = ldpe(csr, jb + 3, ee);
                uint4 g0 = gth(xin, p0, loff), g1 = gth(xin, p1, loff);
                uint4 g2 = gth(xin, p2, loff), g3 = gth(xin, p3, loff);
                fma8(acc[t], p0, g0); fma8(acc[t], p1, g1);
                fma8(acc[t], p2, g2); fma8(acc[t], p3, g3);
            }
        }
    }
}

__global__ __launch_bounds__(256, 4) void prop_mid(
    const int* __restrict__ rcs, const unsigned* __restrict__ csr,
    const unsigned* __restrict__ xin, unsigned* __restrict__ xout,
    int n_nodes, int nch) {
    int grp = threadIdx.x >> 4, gl = threadIdx.x & 15;
    unsigned loff = (unsigned)gl * 4;
    int base = blockIdx.x * 16 + grp;
    float acc[TPROP][8] = {};
    sweep_chunks(rcs, csr, xin, base, loff, n_nodes, nch, acc);
    #pragma unroll
    for (int t = 0; t < TPROP; ++t) {
        int row = base + t * ROWSTRIDE;
        if (row < n_nodes) {
            uint4 o;
            o.x = packbf(acc[t][0], acc[t][1]);
            o.y = packbf(acc[t][2], acc[t][3]);
            o.z = packbf(acc[t][4], acc[t][5]);
            o.w = packbf(acc[t][6], acc[t][7]);
            *(uint4*)(xout + (size_t)row * 64 + loff) = o;
        }
    }
}

// Final layer: x3 = A*x2 fused with out = (emb + x1 + x2 + x3) / 4.
__global__ __launch_bounds__(256, 4) void prop_last(
    const int* __restrict__ rcs, const unsigned* __restrict__ csr,
    const unsigned* __restrict__ x2, const unsigned* __restrict__ x1,
    const float* __restrict__ emb, float* __restrict__ out,
    int n_nodes, int nch) {
    int grp = threadIdx.x >> 4, gl = threadIdx.x & 15;
    unsigned loff = (unsigned)gl * 4;
    int base = blockIdx.x * 16 + grp;
    float acc[TPROP][8] = {};
    sweep_chunks(rcs, csr, x2, base, loff, n_nodes, nch, acc);
    #pragma unroll
    for (int t = 0; t < TPROP; ++t) {
        int row = base + t * ROWSTRIDE;
        if (row < n_nodes) {
            size_t o = (size_t)row * 64 + loff;
            uint4 p1 = *(const uint4*)(x1 + o);
            uint4 p2 = *(const uint4*)(x2 + o);
            const float4* ef = (const float4*)(emb + (size_t)row * 128 + gl * 8);
            float4 e0 = ef[0], e1 = ef[1];
            float4 r0, r1;
            r0.x = (e0.x + blo(p1.x) + blo(p2.x) + acc[t][0]) * 0.25f;
            r0.y = (e0.y + bhi(p1.x) + bhi(p2.x) + acc[t][1]) * 0.25f;
            r0.z = (e0.z + blo(p1.y) + blo(p2.y) + acc[t][2]) * 0.25f;
            r0.w = (e0.w + bhi(p1.y) + bhi(p2.y) + acc[t][3]) * 0.25f;
            r1.x = (e1.x + blo(p1.z) + blo(p2.z) + acc[t][4]) * 0.25f;
            r1.y = (e1.y + bhi(p1.z) + bhi(p2.z) + acc[t][5]) * 0.25f;
            r1.z = (e1.z + blo(p1.w) + blo(p2.w) + acc[t][6]) * 0.25f;
            r1.w = (e1.w + bhi(p1.w) + bhi(p2.w) + acc[t][7]) * 0.25f;
            float4* of = (float4*)(out + (size_t)row * 128 + gl * 8);
            of[0] = r0;
            of[1] = r1;
        }
    }
}

extern "C" void kernel_launch(void* const* d_in, const int* in_sizes, int n_in,
                              void* d_out, int out_size, void* d_ws, size_t ws_size,
                              hipStream_t stream) {
    const float* emb  = (const float*)d_in[0];
    const int*   rows = (const int*)d_in[1];
    const int*   cols = (const int*)d_in[2];
    const float* vals = (const float*)d_in[3];
    float* out = (float*)d_out;

    const int n_nodes = in_sizes[0] / 128;  // 100000
    const int n_edges = in_sizes[1];        // 6400000
    const int NB = (n_nodes + RPB - 1) >> RPB_SHIFT;          // 196 (<= 512)
    const int nch = (n_nodes + (1 << CHSH) - 1) >> CHSH;      // 13 chunks

    char* ws = (char*)d_ws;
    size_t off = 0;
    auto alloc = [&](size_t bytes) -> void* {
        void* p = ws + off;
        off += (bytes + 255) & ~(size_t)255;
        return p;
    };
    unsigned* x0    = (unsigned*)alloc((size_t)n_nodes * 64 * 4);      // 25.6 MB
    unsigned* x1    = (unsigned*)alloc((size_t)n_nodes * 64 * 4);      // 25.6 MB
    unsigned* x2    = (unsigned*)alloc((size_t)n_nodes * 64 * 4);      // 25.6 MB
    unsigned* csr   = (unsigned*)alloc((size_t)n_edges * 4);           // 25.6 MB
    uint2*    pairs = (uint2*)alloc((size_t)n_edges * 8);              // 51.2 MB
    int*      rcs   = (int*)alloc((size_t)(n_nodes * nch + 1) * 4);    // 5.2 MB
    int*      bcount  = (int*)alloc(520 * 4);
    int*      bbase   = (int*)alloc(520 * 4);
    int*      bcursor = (int*)alloc(520 * 4);
    (void)ws_size;

    // ---- Build chunk-sorted CSR via two-level counting sort ----
    hipMemsetAsync(bcount, 0, 520 * 4, stream);
    bucket_count<<<512, 256, 0, stream>>>(rows, bcount, n_edges, NB);
    bucket_scan<<<1, 512, 0, stream>>>(bcount, bbase, bcursor, NB, n_edges);
    const int tiles = (n_edges + 256 * TILE_EPT - 1) / (256 * TILE_EPT);
    bin_edges<<<tiles, 256, 0, stream>>>(rows, cols, vals, bcursor, pairs, n_edges, NB);
    build_csr<<<NB, 256, 0, stream>>>(pairs, bbase, rcs, csr, n_nodes, n_edges, NB, nch);

    // ---- x0 = bf16(emb) ----
    const int n4 = n_nodes * 32;
    init_pack<<<(n4 + 255) / 256, 256, 0, stream>>>((const float4*)emb, (uint2*)x0, n4);

    // ---- 3 layers: one resident wave, chunk-major sweep ----
    prop_mid<<<PROP_GRID, 256, 0, stream>>>(rcs, csr, x0, x1, n_nodes, nch);
    prop_mid<<<PROP_GRID, 256, 0, stream>>>(rcs, csr, x1, x2, n_nodes, nch);
    prop_last<<<PROP_GRID, 256, 0, stream>>>(rcs, csr, x2, x1, emb, out, n_nodes, nch);
}